// Round 1
// baseline (263.893 us; speedup 1.0000x reference)
//
#include <hip/hip_runtime.h>

#define NP 128

// 2 rays per wave: lanes [0..31] own ray r0, lanes [32..63] own ray r1.
// Each lane holds 4 consecutive samples via one float4 load per stream.
// All 6 global loads are issued before any dependent compute -> single
// memory round-trip per wave. Exclusive cumprod = per-lane product of 4
// + 5-step width-32 shfl_up inclusive scan + shift.
__global__ __launch_bounds__(256) void calc_ray_color_kernel(
    const float* __restrict__ rgb,      // [3, NR, NP]
    const float* __restrict__ density,  // [NR, NP]
    const float* __restrict__ dists,    // [NR, NP]
    const float* __restrict__ zvals,    // [NR, NP]
    float* __restrict__ out,            // rgb_res[3*NR] | bg[NR] | depth[NR] | weight[NR*NP]
    int NR)
{
    const int tid = threadIdx.x;
    const int sub = tid & 31;                      // lane within the 32-lane ray group
    const int ray = blockIdx.x * 8 + (tid >> 5);   // 8 rays per 256-thread block
    if (ray >= NR) return;

    const size_t base    = (size_t)ray * NP + 4 * sub;
    const size_t cstride = (size_t)NR * NP;

    // ---- issue ALL loads up-front: one HBM round trip, 96 B/lane in flight ----
    const float4 den = *(const float4*)(density + base);
    const float4 dst = *(const float4*)(dists   + base);
    const float4 z   = *(const float4*)(zvals   + base);
    const float4 c0  = *(const float4*)(rgb + base);
    const float4 c1  = *(const float4*)(rgb + base + cstride);
    const float4 c2  = *(const float4*)(rgb + base + 2 * cstride);

    // alpha and survival terms (same formula as reference for bit-parity)
    const float a0 = 1.0f - __expf(-den.x * dst.x);
    const float a1 = 1.0f - __expf(-den.y * dst.y);
    const float a2 = 1.0f - __expf(-den.z * dst.z);
    const float a3 = 1.0f - __expf(-den.w * dst.w);
    const float x0 = 1.0f - a0 + 1e-10f;
    const float x1 = 1.0f - a1 + 1e-10f;
    const float x2 = 1.0f - a2 + 1e-10f;
    const float x3 = 1.0f - a3 + 1e-10f;

    // per-lane prefix products
    const float p01  = x0 * x1;
    const float p012 = p01 * x2;
    float p = p01 * (x2 * x3);                     // product of all 4

    // inclusive prefix product across the 32-lane group (5 dependent steps)
    #pragma unroll
    for (int off = 1; off < 32; off <<= 1) {
        const float v = __shfl_up(p, off, 32);
        if (sub >= off) p *= v;
    }
    // exclusive
    float excl = __shfl_up(p, 1, 32);
    if (sub == 0) excl = 1.0f;

    const float t0 = excl;
    const float t1 = excl * x0;
    const float t2 = excl * p01;
    const float t3 = excl * p012;
    const float w0 = a0 * t0;
    const float w1 = a1 * t1;
    const float w2 = a2 * t2;
    const float w3 = a3 * t3;

    // weight output (after the 5*NR scalar outputs), fully coalesced float4
    *(float4*)(out + (size_t)5 * NR + base) = make_float4(w0, w1, w2, w3);

    // per-lane partial sums
    float sdep = w0 * z.x + w1 * z.y + w2 * z.z + w3 * z.w;
    float sacc = (w0 + w1) + (w2 + w3);
    float s0   = w0 * c0.x + w1 * c0.y + w2 * c0.z + w3 * c0.w;
    float s1   = w0 * c1.x + w1 * c1.y + w2 * c1.z + w3 * c1.w;
    float s2   = w0 * c2.x + w1 * c2.y + w2 * c2.z + w3 * c2.w;

    // butterfly reduce within each 32-lane group (xor masks <32 never cross
    // the half-wave boundary, so groups stay independent)
    #pragma unroll
    for (int off = 16; off >= 1; off >>= 1) {
        s0   += __shfl_xor(s0, off);
        s1   += __shfl_xor(s1, off);
        s2   += __shfl_xor(s2, off);
        sdep += __shfl_xor(sdep, off);
        sacc += __shfl_xor(sacc, off);
    }

    if (sub == 0) {
        out[ray]                      = s0;
        out[(size_t)NR + ray]         = s1;
        out[2 * (size_t)NR + ray]     = s2;
        out[3 * (size_t)NR + ray]     = 1.0f - sacc;
        out[4 * (size_t)NR + ray]     = sdep;
    }
}

extern "C" void kernel_launch(void* const* d_in, const int* in_sizes, int n_in,
                              void* d_out, int out_size, void* d_ws, size_t ws_size,
                              hipStream_t stream) {
    // d_in[0] = fg_vps  (UNUSED by reference — do not read)
    const float* rgb     = (const float*)d_in[1];
    const float* density = (const float*)d_in[2];
    const float* dists   = (const float*)d_in[3];
    const float* zvals   = (const float*)d_in[4];
    float* out = (float*)d_out;

    const int NR = in_sizes[2] / NP;   // density is [1,1,NR,NP]
    const int rays_per_block = 8;      // 256 threads = 4 waves, 2 rays/wave
    const int grid = (NR + rays_per_block - 1) / rays_per_block;

    calc_ray_color_kernel<<<grid, 256, 0, stream>>>(rgb, density, dists, zvals, out, NR);
}